// Round 2
// baseline (18944.807 us; speedup 1.0000x reference)
//
#include <hip/hip_runtime.h>
#include <hip/hip_bf16.h>

// ResNetTTT: fp32. Round 2: ttt_kernel restructured to 512 threads (2 waves/SIMD),
// W2 column copy split per-wave (32 regs), next-step input prefetch.

#define ERF_CF 0.70710678118654752f
#define PDF_CF 0.3989422804014327f
#define ETA 0.025f   // TTT_LR / MB = 0.1/4

__device__ __forceinline__ float wsum(float v) {
#pragma unroll
  for (int o = 32; o > 0; o >>= 1) v += __shfl_xor(v, o, 64);
  return v;
}

// ---------------------------------------------------------------------------
// prep: transpose conv weights into GEMM-friendly [k][co] layout
// ---------------------------------------------------------------------------
__global__ void prep_w(const float* __restrict__ c1w, const float* __restrict__ cw,
                       float* __restrict__ wt1, float* __restrict__ wt) {
  int id = blockIdx.x * 256 + threadIdx.x;
  if (id < 16384) {
    int ci = id >> 8, co = id & 255;
    wt1[id] = c1w[co * 64 + ci];
  }
  int id2 = id - 16384;
  if (id2 >= 0 && id2 < 1572864) {
    int cv = id2 / 196608;
    int r = id2 - cv * 196608;
    int k = r >> 8, co = r & 255;
    int tt = k >> 8, ci = k & 255;
    wt[id2] = cw[((cv * 256 + co) * 256 + ci) * 3 + tt];
  }
}

__global__ void zero_halo(float* __restrict__ bufA, float* __restrict__ bufB) {
  int id = blockIdx.x * 256 + threadIdx.x;  // 0..4095
  int c = id & 255;
  int row = (id >> 8) & 1;
  int b = (id >> 9) & 3;
  float* p = (id >> 11) ? bufB : bufA;
  p[(b * 1026 + row * 1025) * 256 + c] = 0.0f;
}

// ---------------------------------------------------------------------------
// Generic tiled fp32 GEMM (unchanged from round 1)
// ---------------------------------------------------------------------------
template <int BIAS, int RELU, int RES, int OST, int ACC>
__global__ __launch_bounds__(256) void gemm_k(
    const float* __restrict__ A, const float* __restrict__ Wt,
    const float* __restrict__ bias, const float* __restrict__ res,
    float* __restrict__ out, float* __restrict__ accp,
    int M, int N, int K, int lda, int haloA) {
  __shared__ float As[16][68];
  __shared__ float Bs[16][64];
  const int tid = threadIdx.x;
  const int bm = blockIdx.x * 64, bn = blockIdx.y * 64;
  const int tx = tid & 15, ty = tid >> 4;
  float acc[4][4] = {};

  for (int k0 = 0; k0 < K; k0 += 16) {
#pragma unroll
    for (int i = 0; i < 4; ++i) {
      int idx = tid + i * 256;
      int kk = idx & 15, mm = idx >> 4;
      int m = bm + mm;
      int rb = m * lda + (haloA ? ((m >> 10) << 9) : 0);
      As[kk][mm] = A[rb + k0 + kk];
    }
#pragma unroll
    for (int i = 0; i < 4; ++i) {
      int idx = tid + i * 256;
      int nn = idx & 63, kk = idx >> 6;
      Bs[kk][nn] = Wt[(k0 + kk) * N + bn + nn];
    }
    __syncthreads();
#pragma unroll
    for (int kk = 0; kk < 16; ++kk) {
      float4 av = *(const float4*)&As[kk][ty * 4];
      float4 bv = *(const float4*)&Bs[kk][tx * 4];
      float aa[4] = {av.x, av.y, av.z, av.w};
      float bb[4] = {bv.x, bv.y, bv.z, bv.w};
#pragma unroll
      for (int i = 0; i < 4; ++i)
#pragma unroll
        for (int j = 0; j < 4; ++j) acc[i][j] = fmaf(aa[i], bb[j], acc[i][j]);
    }
    __syncthreads();
  }

  const int n0 = bn + tx * 4;
#pragma unroll
  for (int i = 0; i < 4; ++i) {
    int m = bm + ty * 4 + i;
    int b_ = m >> 10, l = m & 1023;
    float v[4];
#pragma unroll
    for (int j = 0; j < 4; ++j) {
      float x = acc[i][j];
      if constexpr (BIAS) x += bias[n0 + j];
      if constexpr (RELU) x = fmaxf(x, 0.0f);
      if constexpr (RES) x += res[m * N + n0 + j];
      v[j] = x;
    }
    float4 vv = make_float4(v[0], v[1], v[2], v[3]);
    if constexpr (OST == 0) {
      *(float4*)&out[m * N + n0] = vv;
    } else if constexpr (OST == 1) {
      *(float4*)&out[(b_ * 1026 + l + 1) * 256 + n0] = vv;
    } else {
      int hq = n0 >> 6;
      int oidx = (((b_ * 4 + hq) * 1024 + l) << 6) + (n0 & 63);
      *(float4*)&out[oidx] = vv;
    }
    if constexpr (ACC == 1) {
      *(float4*)&accp[m * 256 + n0] = vv;
    } else if constexpr (ACC == 2) {
      float4 s = *(const float4*)&accp[m * 256 + n0];
      s.x += vv.x; s.y += vv.y; s.z += vv.z; s.w += vv.w;
      *(float4*)&accp[m * 256 + n0] = s;
    }
  }
}

// ---------------------------------------------------------------------------
// LayerNorm over last dim (256). 64 threads = 1 wave per row.
// ---------------------------------------------------------------------------
__global__ __launch_bounds__(64) void ln_kernel(const float* __restrict__ in,
                                                float* __restrict__ o,
                                                const float* __restrict__ w,
                                                const float* __restrict__ bb,
                                                float eps) {
  int row = blockIdx.x;
  int l = threadIdx.x;
  float4 v = ((const float4*)(in + (long)row * 256))[l];
  float s = wsum(v.x + v.y + v.z + v.w);
  float mu = s * (1.0f / 256.0f);
  float dx = v.x - mu, dy = v.y - mu, dz = v.z - mu, dw = v.w - mu;
  float ss = wsum(dx * dx + dy * dy + dz * dz + dw * dw);
  float rstd = rsqrtf(ss * (1.0f / 256.0f) + eps);
  float4 wv = ((const float4*)w)[l];
  float4 bv = ((const float4*)bb)[l];
  float4 r;
  r.x = wv.x * dx * rstd + bv.x;
  r.y = wv.y * dy * rstd + bv.y;
  r.z = wv.z * dz * rstd + bv.z;
  r.w = wv.w * dw * rstd + bv.w;
  ((float4*)(o + (long)row * 256))[l] = r;
}

// ---------------------------------------------------------------------------
// TTT scan: one block of 512 threads (8 waves, 2/SIMD) per (b,h) chain.
// Thread t: c = t&255 (column), g = t>>8 (rows {2g,2g+1}); w8 = t>>6, lane = t&63.
// Registers: w1[64] = W1 column c; w2row[64] = W2 row c; w2colR[32] = W2[kb+kk][lane].
// ---------------------------------------------------------------------------
__global__ __launch_bounds__(512) void ttt_kernel(
    const float* __restrict__ XQ, const float* __restrict__ XK,
    const float* __restrict__ XV, const float* __restrict__ W1i,
    const float* __restrict__ B1i, const float* __restrict__ W2i,
    const float* __restrict__ B2i, const float* __restrict__ LNW,
    const float* __restrict__ LNB, float* __restrict__ outp) {
  const int bh = blockIdx.x;
  const int b = bh >> 2, h = bh & 3;
  const int t = threadIdx.x;      // 0..511
  const int w8 = t >> 6;          // 0..7
  const int lane = t & 63;
  const int c = t & 255;          // column 0..255
  const int g = t >> 8;           // row-group 0/1
  const int m0 = 2 * g, m1 = 2 * g + 1;
  const int kb = w8 * 32;         // k-slice base for Z2 partials

  __shared__ float xkL[256], xvL[256], xqL[256];
  __shared__ float X2s[4][256];
  __shared__ float gZ2s[4][64];
  __shared__ float gZ1s[4][256];
  __shared__ float redS[8][4][64];
  __shared__ float b2s[64], lwS[64], lbS[64];

  float w1[64], w2row[64], w2colR[32];
#pragma unroll
  for (int k = 0; k < 64; ++k) w1[k] = W1i[(h * 64 + k) * 256 + c];
  float b1r = B1i[h * 256 + c];
#pragma unroll
  for (int p = 0; p < 64; ++p) w2row[p] = W2i[(h * 256 + c) * 64 + p];
#pragma unroll
  for (int kk = 0; kk < 32; ++kk) w2colR[kk] = W2i[(h * 256 + kb + kk) * 64 + lane];
  if (t < 64) {
    b2s[t] = B2i[h * 64 + t];
    lwS[t] = LNW[h * 64 + t];
    lbS[t] = LNB[h * 64 + t];
  }

  const long chain = (long)bh * (1024 * 64);
  float rk = 0.0f, rv = 0.0f, rq = 0.0f;
  if (t < 256) { rk = XK[chain + t]; rv = XV[chain + t]; }
  else         { rq = XQ[chain + (t - 256)]; }
  __syncthreads();

  for (int n = 0; n < 256; ++n) {
    // commit prefetched inputs to LDS
    if (t < 256) { xkL[t] = rk; xvL[t] = rv; } else { xqL[t - 256] = rq; }
    __syncthreads();  // B1

    // ---- A: Z1 rows m0,m1 col c ; X2 = gelu ----
    float am0 = b1r, am1 = b1r;
    {
      const float* xk0 = &xkL[m0 * 64];
      const float* xk1 = &xkL[m1 * 64];
#pragma unroll
      for (int k4 = 0; k4 < 64; k4 += 4) {
        float4 a0 = *(const float4*)&xk0[k4];
        float4 a1 = *(const float4*)&xk1[k4];
        am0 = fmaf(a0.x, w1[k4], am0);
        am0 = fmaf(a0.y, w1[k4 + 1], am0);
        am0 = fmaf(a0.z, w1[k4 + 2], am0);
        am0 = fmaf(a0.w, w1[k4 + 3], am0);
        am1 = fmaf(a1.x, w1[k4], am1);
        am1 = fmaf(a1.y, w1[k4 + 1], am1);
        am1 = fmaf(a1.z, w1[k4 + 2], am1);
        am1 = fmaf(a1.w, w1[k4 + 3], am1);
      }
    }
    const float z10 = am0, z11 = am1;
    const float er0 = erff(z10 * ERF_CF), er1 = erff(z11 * ERF_CF);
    const float x20 = 0.5f * z10 * (1.0f + er0);
    const float x21 = 0.5f * z11 * (1.0f + er1);
    X2s[m0][c] = x20;
    X2s[m1][c] = x21;
    __syncthreads();  // B2

    // ---- B: Z2 partials over k-slice [kb, kb+32), column lane ----
    {
      float pp0 = 0, pp1 = 0, pp2 = 0, pp3 = 0;
#pragma unroll
      for (int k4 = 0; k4 < 32; k4 += 4) {
        float4 y0 = *(const float4*)&X2s[0][kb + k4];
        float4 y1 = *(const float4*)&X2s[1][kb + k4];
        float4 y2 = *(const float4*)&X2s[2][kb + k4];
        float4 y3 = *(const float4*)&X2s[3][kb + k4];
#define BP(J, C)                              \
  {                                           \
    float wv = w2colR[k4 + J];                \
    pp0 = fmaf(y0.C, wv, pp0);                \
    pp1 = fmaf(y1.C, wv, pp1);                \
    pp2 = fmaf(y2.C, wv, pp2);                \
    pp3 = fmaf(y3.C, wv, pp3);                \
  }
        BP(0, x) BP(1, y) BP(2, z) BP(3, w)
#undef BP
      }
      redS[w8][0][lane] = pp0;
      redS[w8][1][lane] = pp1;
      redS[w8][2][lane] = pp2;
      redS[w8][3][lane] = pp3;
    }
    __syncthreads();  // B3

    // ---- C: reduce + LN-l2-bwd -> gZ2s (waves 0-3: row m=w8, col lane) ----
    if (t < 256) {
      float z2 = b2s[lane];
#pragma unroll
      for (int q = 0; q < 8; ++q) z2 += redS[q][w8][lane];
      float mu = wsum(z2) * (1.0f / 64.0f);
      float dv = z2 - mu;
      float var = wsum(dv * dv) * (1.0f / 64.0f);
      float stdv = sqrtf(var + 1e-6f);
      float zhat = dv / stdv;
      float lwv = lwS[lane], lbv = lbS[lane];
      float tgt = xvL[w8 * 64 + lane] - xkL[w8 * 64 + lane];
      float gg = lwv * (lwv * zhat + lbv - tgt);
      float gs = wsum(gg) * (1.0f / 64.0f);
      float gzs = wsum(gg * zhat) * (1.0f / 64.0f);
      gZ2s[w8][lane] = (gg - gs - zhat * gzs) / stdv;
    }
    __syncthreads();  // B4

    // prefetch next step's inputs (hidden under D/E/F compute)
    if (n + 1 < 256) {
      const long nb = chain + (long)(n + 1) * 256;
      if (t < 256) { rk = XK[nb + t]; rv = XV[nb + t]; }
      else         { rq = XQ[nb + (t - 256)]; }
    }

    // ---- D: gZ1 rows m0,m1 (uses OLD w2row) fused with w2row update ----
    float gz10, gz11;
    {
      const float xa0 = X2s[0][c], xa1 = X2s[1][c];
      const float xa2 = X2s[2][c], xa3 = X2s[3][c];
      const float* gzA = &gZ2s[m0][0];
      const float* gzB = &gZ2s[m1][0];
      float sD0 = 0, sD1 = 0;
#pragma unroll
      for (int p4 = 0; p4 < 64; p4 += 4) {
        float4 q0 = *(const float4*)&gZ2s[0][p4];
        float4 q1 = *(const float4*)&gZ2s[1][p4];
        float4 q2 = *(const float4*)&gZ2s[2][p4];
        float4 q3 = *(const float4*)&gZ2s[3][p4];
        float4 ga = *(const float4*)&gzA[p4];
        float4 gb = *(const float4*)&gzB[p4];
#define DS(J, C)                                              \
  {                                                           \
    float wv = w2row[p4 + J];                                 \
    sD0 = fmaf(ga.C, wv, sD0);                                \
    sD1 = fmaf(gb.C, wv, sD1);                                \
    float u = xa0 * q0.C;                                     \
    u = fmaf(xa1, q1.C, u);                                   \
    u = fmaf(xa2, q2.C, u);                                   \
    u = fmaf(xa3, q3.C, u);                                   \
    w2row[p4 + J] = fmaf(-ETA, u, wv);                        \
  }
        DS(0, x) DS(1, y) DS(2, z) DS(3, w)
#undef DS
      }
      const float gp0 = 0.5f * (1.0f + er0) + z10 * expf(-0.5f * z10 * z10) * PDF_CF;
      const float gp1 = 0.5f * (1.0f + er1) + z11 * expf(-0.5f * z11 * z11) * PDF_CF;
      gz10 = sD0 * gp0;
      gz11 = sD1 * gp1;
      gZ1s[m0][c] = gz10;
      gZ1s[m1][c] = gz11;
    }
    __syncthreads();  // B5

    // ---- E: W1/b1 update (fixed m-order from LDS -> both g-copies identical) ----
    {
      const float ga0 = gZ1s[0][c], ga1 = gZ1s[1][c];
      const float ga2 = gZ1s[2][c], ga3 = gZ1s[3][c];
      b1r = fmaf(-ETA, ((ga0 + ga1) + ga2) + ga3, b1r);
#pragma unroll
      for (int k4 = 0; k4 < 64; k4 += 4) {
        float4 x0 = *(const float4*)&xkL[k4];
        float4 x1 = *(const float4*)&xkL[64 + k4];
        float4 x2v = *(const float4*)&xkL[128 + k4];
        float4 x3v = *(const float4*)&xkL[192 + k4];
#define W1S(J, C)                                             \
  {                                                           \
    float u = x0.C * ga0;                                     \
    u = fmaf(x1.C, ga1, u);                                   \
    u = fmaf(x2v.C, ga2, u);                                  \
    u = fmaf(x3v.C, ga3, u);                                  \
    w1[k4 + J] = fmaf(-ETA, u, w1[k4 + J]);                   \
  }
        W1S(0, x) W1S(1, y) W1S(2, z) W1S(3, w)
#undef W1S
      }
    }
    // ---- E2: w2colR update ----
    {
      const float go0 = gZ2s[0][lane], go1 = gZ2s[1][lane];
      const float go2 = gZ2s[2][lane], go3 = gZ2s[3][lane];
#pragma unroll
      for (int k4 = 0; k4 < 32; k4 += 4) {
        float4 y0 = *(const float4*)&X2s[0][kb + k4];
        float4 y1 = *(const float4*)&X2s[1][kb + k4];
        float4 y2 = *(const float4*)&X2s[2][kb + k4];
        float4 y3 = *(const float4*)&X2s[3][kb + k4];
#define W2S(J, C)                                             \
  {                                                           \
    float u = y0.C * go0;                                     \
    u = fmaf(y1.C, go1, u);                                   \
    u = fmaf(y2.C, go2, u);                                   \
    u = fmaf(y3.C, go3, u);                                   \
    w2colR[k4 + J] = fmaf(-ETA, u, w2colR[k4 + J]);           \
  }
        W2S(0, x) W2S(1, y) W2S(2, z) W2S(3, w)
#undef W2S
      }
    }
    if (t < 64) {
      float gb2 = ((gZ2s[0][t] + gZ2s[1][t]) + gZ2s[2][t]) + gZ2s[3][t];
      b2s[t] = fmaf(-ETA, gb2, b2s[t]);
    }
    __syncthreads();  // B6 (X2s & gZ1s reads done)

    // ---- F: Z1q rows m0,m1 with updated W1 ; gelu -> X2s ----
    {
      float aq0 = b1r, aq1 = b1r;
      const float* xq0 = &xqL[m0 * 64];
      const float* xq1 = &xqL[m1 * 64];
#pragma unroll
      for (int k4 = 0; k4 < 64; k4 += 4) {
        float4 a0 = *(const float4*)&xq0[k4];
        float4 a1 = *(const float4*)&xq1[k4];
        aq0 = fmaf(a0.x, w1[k4], aq0);
        aq0 = fmaf(a0.y, w1[k4 + 1], aq0);
        aq0 = fmaf(a0.z, w1[k4 + 2], aq0);
        aq0 = fmaf(a0.w, w1[k4 + 3], aq0);
        aq1 = fmaf(a1.x, w1[k4], aq1);
        aq1 = fmaf(a1.y, w1[k4 + 1], aq1);
        aq1 = fmaf(a1.z, w1[k4 + 2], aq1);
        aq1 = fmaf(a1.w, w1[k4 + 3], aq1);
      }
      X2s[m0][c] = 0.5f * aq0 * (1.0f + erff(aq0 * ERF_CF));
      X2s[m1][c] = 0.5f * aq1 * (1.0f + erff(aq1 * ERF_CF));
    }
    __syncthreads();  // B7

    // ---- G: Z2q partials with updated w2colR ----
    {
      float pp0 = 0, pp1 = 0, pp2 = 0, pp3 = 0;
#pragma unroll
      for (int k4 = 0; k4 < 32; k4 += 4) {
        float4 y0 = *(const float4*)&X2s[0][kb + k4];
        float4 y1 = *(const float4*)&X2s[1][kb + k4];
        float4 y2 = *(const float4*)&X2s[2][kb + k4];
        float4 y3 = *(const float4*)&X2s[3][kb + k4];
#define GP(J, C)                              \
  {                                           \
    float wv = w2colR[k4 + J];                \
    pp0 = fmaf(y0.C, wv, pp0);                \
    pp1 = fmaf(y1.C, wv, pp1);                \
    pp2 = fmaf(y2.C, wv, pp2);                \
    pp3 = fmaf(y3.C, wv, pp3);                \
  }
        GP(0, x) GP(1, y) GP(2, z) GP(3, w)
#undef GP
      }
      redS[w8][0][lane] = pp0;
      redS[w8][1][lane] = pp1;
      redS[w8][2][lane] = pp2;
      redS[w8][3][lane] = pp3;
    }
    __syncthreads();  // B8

    // ---- Gr: reduce + LN fwd + residual + output ----
    if (t < 256) {
      float z2 = b2s[lane];
#pragma unroll
      for (int q = 0; q < 8; ++q) z2 += redS[q][w8][lane];
      float mu = wsum(z2) * (1.0f / 64.0f);
      float dv = z2 - mu;
      float var = wsum(dv * dv) * (1.0f / 64.0f);
      float rstd = rsqrtf(var + 1e-6f);
      float val = lwS[lane] * dv * rstd + lbS[lane] + xqL[w8 * 64 + lane];
      outp[((long)(b * 1024 + n * 4 + w8)) * 256 + h * 64 + lane] = val;
    }
    __syncthreads();  // B9 (protect xk/xv/xq/redS overwrite next iter)
  }
}

// final (4096,64) @ (64,1) + b
__global__ __launch_bounds__(256) void fc3_kernel(const float* __restrict__ f2,
                                                  const float* __restrict__ w,
                                                  const float* __restrict__ bias,
                                                  float* __restrict__ o) {
  int m = blockIdx.x * 4 + (threadIdx.x >> 6);
  int lane = threadIdx.x & 63;
  float v = f2[m * 64 + lane] * w[lane];
  v = wsum(v);
  if (lane == 0) o[m] = v + bias[0];
}

// ---------------------------------------------------------------------------
extern "C" void kernel_launch(void* const* d_in, const int* in_sizes, int n_in,
                              void* d_out, int out_size, void* d_ws, size_t ws_size,
                              hipStream_t stream) {
  const float* x       = (const float*)d_in[0];
  const float* conv1_w = (const float*)d_in[1];
  const float* conv1_b = (const float*)d_in[2];
  const float* convs_w = (const float*)d_in[3];
  const float* convs_b = (const float*)d_in[4];
  const float* ln_w    = (const float*)d_in[5];
  const float* ln_b    = (const float*)d_in[6];
  const float* wq      = (const float*)d_in[7];
  const float* wk      = (const float*)d_in[8];
  const float* wv      = (const float*)d_in[9];
  const float* wo      = (const float*)d_in[10];
  const float* ttt_W1  = (const float*)d_in[11];
  const float* ttt_b1  = (const float*)d_in[12];
  const float* ttt_W2  = (const float*)d_in[13];
  const float* ttt_b2  = (const float*)d_in[14];
  const float* ttt_lnw = (const float*)d_in[15];
  const float* ttt_lnb = (const float*)d_in[16];
  const float* fc_w    = (const float*)d_in[17];
  const float* fc_b    = (const float*)d_in[18];
  const float* fc2_w   = (const float*)d_in[19];
  const float* fc2_b   = (const float*)d_in[20];
  const float* fc3_w   = (const float*)d_in[21];
  const float* fc3_b   = (const float*)d_in[22];

  float* ws = (float*)d_ws;
  float* wt1  = ws + 0;                       // 16384
  float* wt   = ws + 16384;                   // 1572864
  float* bufA = ws + 1589248;                 // 1050624 (B,L+2,256)
  float* bufB = ws + 2639872;                 // 1050624
  float* sum4 = ws + 3690496;                 // 1048576 (B,L,256)
  float* tln  = ws + 4739072;                 // 1048576
  float* XQ   = ws + 5787648;                 // 1048576 (B,H,L,64)
  float* XK   = ws + 6836224;                 // 1048576
  float* XV   = ws + 7884800;                 // 1048576
  float* tout = ws + 8933376;                 // 1048576
  float* tfull = sum4;
  float* h2    = bufA;
  float* f1    = XQ;
  float* f2    = tout;

  const int M = 4096;
  dim3 blk(256);

  zero_halo<<<16, blk, 0, stream>>>(bufA, bufB);
  prep_w<<<6208, blk, 0, stream>>>(conv1_w, convs_w, wt1, wt);

  // conv1 (1x1) + relu -> bufA (halo store)
  gemm_k<1, 1, 0, 1, 0><<<dim3(64, 4), blk, 0, stream>>>(
      x, wt1, conv1_b, nullptr, bufA, nullptr, M, 256, 64, 64, 0);

  // 8 sequential 3-tap convs, accumulate acts 1,3,5,7 into sum4
  for (int i = 0; i < 8; ++i) {
    const float* in = (i % 2 == 0) ? bufA : bufB;
    float* out = (i % 2 == 0) ? bufB : bufA;
    const float* wp = wt + (size_t)i * 196608;
    const float* bp = convs_b + i * 256;
    if (i == 1)
      gemm_k<1, 1, 0, 1, 1><<<dim3(64, 4), blk, 0, stream>>>(
          in, wp, bp, nullptr, out, sum4, M, 256, 768, 256, 1);
    else if (i == 3 || i == 5 || i == 7)
      gemm_k<1, 1, 0, 1, 2><<<dim3(64, 4), blk, 0, stream>>>(
          in, wp, bp, nullptr, out, sum4, M, 256, 768, 256, 1);
    else
      gemm_k<1, 1, 0, 1, 0><<<dim3(64, 4), blk, 0, stream>>>(
          in, wp, bp, nullptr, out, sum4, M, 256, 768, 256, 1);
  }

  // LN #1
  ln_kernel<<<4096, 64, 0, stream>>>(sum4, tln, ln_w, ln_b, 1e-5f);

  // QKV projections with (B,H,L,64) scatter
  gemm_k<0, 0, 0, 2, 0><<<dim3(64, 4), blk, 0, stream>>>(
      tln, wq, nullptr, nullptr, XQ, nullptr, M, 256, 256, 256, 0);
  gemm_k<0, 0, 0, 2, 0><<<dim3(64, 4), blk, 0, stream>>>(
      tln, wk, nullptr, nullptr, XK, nullptr, M, 256, 256, 256, 0);
  gemm_k<0, 0, 0, 2, 0><<<dim3(64, 4), blk, 0, stream>>>(
      tln, wv, nullptr, nullptr, XV, nullptr, M, 256, 256, 256, 0);

  // TTT scan: 16 chains, 512 threads each
  ttt_kernel<<<16, dim3(512), 0, stream>>>(XQ, XK, XV, ttt_W1, ttt_b1, ttt_W2,
                                           ttt_b2, ttt_lnw, ttt_lnb, tout);

  // x + out@wo  (residual = tln)
  gemm_k<0, 0, 1, 0, 0><<<dim3(64, 4), blk, 0, stream>>>(
      tout, wo, nullptr, tln, tfull, nullptr, M, 256, 256, 256, 0);

  // LN #2
  ln_kernel<<<4096, 64, 0, stream>>>(tfull, h2, ln_w, ln_b, 1e-5f);

  // fc (256->512), fc2 (512->64), fc3 (64->1)
  gemm_k<1, 0, 0, 0, 0><<<dim3(64, 8), blk, 0, stream>>>(
      h2, fc_w, fc_b, nullptr, f1, nullptr, M, 512, 256, 256, 0);
  gemm_k<1, 0, 0, 0, 0><<<dim3(64, 1), blk, 0, stream>>>(
      f1, fc2_w, fc2_b, nullptr, f2, nullptr, M, 64, 512, 512, 0);
  fc3_kernel<<<1024, blk, 0, stream>>>(f2, fc3_w, fc3_b, (float*)d_out);
}

// Round 3
// 8470.793 us; speedup vs baseline: 2.2365x; 2.2365x over previous
//
#include <hip/hip_runtime.h>
#include <hip/hip_bf16.h>

// ResNetTTT: fp32. Round 3: ttt_kernel back to 256 threads; W2 columns served
// from LDS (rotation swizzle), W2 rows + W1 columns in registers -> no spill.

#define ERF_CF 0.70710678118654752f
#define PDF_CF 0.3989422804014327f
#define ETA 0.025f   // TTT_LR / MB = 0.1/4

__device__ __forceinline__ float wsum(float v) {
#pragma unroll
  for (int o = 32; o > 0; o >>= 1) v += __shfl_xor(v, o, 64);
  return v;
}

// ---------------------------------------------------------------------------
// prep: transpose conv weights into GEMM-friendly [k][co] layout
// ---------------------------------------------------------------------------
__global__ void prep_w(const float* __restrict__ c1w, const float* __restrict__ cw,
                       float* __restrict__ wt1, float* __restrict__ wt) {
  int id = blockIdx.x * 256 + threadIdx.x;
  if (id < 16384) {
    int ci = id >> 8, co = id & 255;
    wt1[id] = c1w[co * 64 + ci];
  }
  int id2 = id - 16384;
  if (id2 >= 0 && id2 < 1572864) {
    int cv = id2 / 196608;
    int r = id2 - cv * 196608;
    int k = r >> 8, co = r & 255;
    int tt = k >> 8, ci = k & 255;
    wt[id2] = cw[((cv * 256 + co) * 256 + ci) * 3 + tt];
  }
}

__global__ void zero_halo(float* __restrict__ bufA, float* __restrict__ bufB) {
  int id = blockIdx.x * 256 + threadIdx.x;  // 0..4095
  int c = id & 255;
  int row = (id >> 8) & 1;
  int b = (id >> 9) & 3;
  float* p = (id >> 11) ? bufB : bufA;
  p[(b * 1026 + row * 1025) * 256 + c] = 0.0f;
}

// ---------------------------------------------------------------------------
// Generic tiled fp32 GEMM (unchanged)
// ---------------------------------------------------------------------------
template <int BIAS, int RELU, int RES, int OST, int ACC>
__global__ __launch_bounds__(256) void gemm_k(
    const float* __restrict__ A, const float* __restrict__ Wt,
    const float* __restrict__ bias, const float* __restrict__ res,
    float* __restrict__ out, float* __restrict__ accp,
    int M, int N, int K, int lda, int haloA) {
  __shared__ float As[16][68];
  __shared__ float Bs[16][64];
  const int tid = threadIdx.x;
  const int bm = blockIdx.x * 64, bn = blockIdx.y * 64;
  const int tx = tid & 15, ty = tid >> 4;
  float acc[4][4] = {};

  for (int k0 = 0; k0 < K; k0 += 16) {
#pragma unroll
    for (int i = 0; i < 4; ++i) {
      int idx = tid + i * 256;
      int kk = idx & 15, mm = idx >> 4;
      int m = bm + mm;
      int rb = m * lda + (haloA ? ((m >> 10) << 9) : 0);
      As[kk][mm] = A[rb + k0 + kk];
    }
#pragma unroll
    for (int i = 0; i < 4; ++i) {
      int idx = tid + i * 256;
      int nn = idx & 63, kk = idx >> 6;
      Bs[kk][nn] = Wt[(k0 + kk) * N + bn + nn];
    }
    __syncthreads();
#pragma unroll
    for (int kk = 0; kk < 16; ++kk) {
      float4 av = *(const float4*)&As[kk][ty * 4];
      float4 bv = *(const float4*)&Bs[kk][tx * 4];
      float aa[4] = {av.x, av.y, av.z, av.w};
      float bb[4] = {bv.x, bv.y, bv.z, bv.w};
#pragma unroll
      for (int i = 0; i < 4; ++i)
#pragma unroll
        for (int j = 0; j < 4; ++j) acc[i][j] = fmaf(aa[i], bb[j], acc[i][j]);
    }
    __syncthreads();
  }

  const int n0 = bn + tx * 4;
#pragma unroll
  for (int i = 0; i < 4; ++i) {
    int m = bm + ty * 4 + i;
    int b_ = m >> 10, l = m & 1023;
    float v[4];
#pragma unroll
    for (int j = 0; j < 4; ++j) {
      float x = acc[i][j];
      if constexpr (BIAS) x += bias[n0 + j];
      if constexpr (RELU) x = fmaxf(x, 0.0f);
      if constexpr (RES) x += res[m * N + n0 + j];
      v[j] = x;
    }
    float4 vv = make_float4(v[0], v[1], v[2], v[3]);
    if constexpr (OST == 0) {
      *(float4*)&out[m * N + n0] = vv;
    } else if constexpr (OST == 1) {
      *(float4*)&out[(b_ * 1026 + l + 1) * 256 + n0] = vv;
    } else {
      int hq = n0 >> 6;
      int oidx = (((b_ * 4 + hq) * 1024 + l) << 6) + (n0 & 63);
      *(float4*)&out[oidx] = vv;
    }
    if constexpr (ACC == 1) {
      *(float4*)&accp[m * 256 + n0] = vv;
    } else if constexpr (ACC == 2) {
      float4 s = *(const float4*)&accp[m * 256 + n0];
      s.x += vv.x; s.y += vv.y; s.z += vv.z; s.w += vv.w;
      *(float4*)&accp[m * 256 + n0] = s;
    }
  }
}

// ---------------------------------------------------------------------------
// LayerNorm over last dim (256). 64 threads = 1 wave per row.
// ---------------------------------------------------------------------------
__global__ __launch_bounds__(64) void ln_kernel(const float* __restrict__ in,
                                                float* __restrict__ o,
                                                const float* __restrict__ w,
                                                const float* __restrict__ bb,
                                                float eps) {
  int row = blockIdx.x;
  int l = threadIdx.x;
  float4 v = ((const float4*)(in + (long)row * 256))[l];
  float s = wsum(v.x + v.y + v.z + v.w);
  float mu = s * (1.0f / 256.0f);
  float dx = v.x - mu, dy = v.y - mu, dz = v.z - mu, dw = v.w - mu;
  float ss = wsum(dx * dx + dy * dy + dz * dz + dw * dw);
  float rstd = rsqrtf(ss * (1.0f / 256.0f) + eps);
  float4 wv = ((const float4*)w)[l];
  float4 bv = ((const float4*)bb)[l];
  float4 r;
  r.x = wv.x * dx * rstd + bv.x;
  r.y = wv.y * dy * rstd + bv.y;
  r.z = wv.z * dz * rstd + bv.z;
  r.w = wv.w * dw * rstd + bv.w;
  ((float4*)(o + (long)row * 256))[l] = r;
}

// ---------------------------------------------------------------------------
// TTT scan: one block of 256 threads per (b,h) chain.
// Thread t = column c (0..255); w = t>>6 (row m / k-slice), lane = t&63.
// Registers: w1[64] = W1[:,c]; w2r[64] = W2[c,:].
// LDS: full W2 with rotation swizzle W2L[k][(j+k)&63] for conflict-free
// column reads (stages B/G) and row commit writes (after stage D).
// ---------------------------------------------------------------------------
__global__ __launch_bounds__(256, 1) void ttt_kernel(
    const float* __restrict__ XQ, const float* __restrict__ XK,
    const float* __restrict__ XV, const float* __restrict__ W1i,
    const float* __restrict__ B1i, const float* __restrict__ W2i,
    const float* __restrict__ B2i, const float* __restrict__ LNW,
    const float* __restrict__ LNB, float* __restrict__ outp) {
  const int bh = blockIdx.x;
  const int b = bh >> 2, h = bh & 3;
  const int t = threadIdx.x;   // column c
  const int w = t >> 6, lane = t & 63;
  const int kb = w << 6;       // k-slice base for stages B/G

  __shared__ float xkL[256], xvL[256], xqL[256];
  __shared__ float X2s[4][256];
  __shared__ float gZ2s[4][64];
  __shared__ float redS[4][4][64];
  __shared__ float b2s[64], lwS[64], lbS[64];
  __shared__ float W2L[256][64];

  float w1[64], w2r[64];
#pragma unroll
  for (int k = 0; k < 64; ++k) w1[k] = W1i[(h * 64 + k) * 256 + t];
  float b1r = B1i[h * 256 + t];
#pragma unroll
  for (int p4 = 0; p4 < 64; p4 += 4) {
    float4 v = *(const float4*)&W2i[(h * 256 + t) * 64 + p4];
    w2r[p4] = v.x; w2r[p4 + 1] = v.y; w2r[p4 + 2] = v.z; w2r[p4 + 3] = v.w;
  }
  // W2 -> LDS, rotation swizzle
#pragma unroll
  for (int i = 0; i < 64; ++i) {
    int id = t + i * 256;
    int k = id >> 6, j = id & 63;
    W2L[k][(j + k) & 63] = W2i[(h * 256 + k) * 64 + j];
  }
  if (t < 64) {
    b2s[t] = B2i[h * 64 + t];
    lwS[t] = LNW[h * 64 + t];
    lbS[t] = LNB[h * 64 + t];
  }

  const long chain = (long)bh * (1024 * 64);
  float rk = XK[chain + t], rv = XV[chain + t], rq = XQ[chain + t];
  __syncthreads();

  for (int n = 0; n < 256; ++n) {
    xkL[t] = rk; xvL[t] = rv; xqL[t] = rq;
    __syncthreads();  // B1

    // ---- A: Z1[m][c] = xk@W1 + b1 ; X2 = gelu(Z1) ----
    float am0 = b1r, am1 = b1r, am2 = b1r, am3 = b1r;
#pragma unroll
    for (int k4 = 0; k4 < 64; k4 += 4) {
      float4 a0 = *(const float4*)&xkL[k4];
      float4 a1 = *(const float4*)&xkL[64 + k4];
      float4 a2 = *(const float4*)&xkL[128 + k4];
      float4 a3 = *(const float4*)&xkL[192 + k4];
      float w0 = w1[k4], wA = w1[k4 + 1], wB = w1[k4 + 2], wC = w1[k4 + 3];
      am0 = fmaf(a0.x, w0, am0); am0 = fmaf(a0.y, wA, am0);
      am0 = fmaf(a0.z, wB, am0); am0 = fmaf(a0.w, wC, am0);
      am1 = fmaf(a1.x, w0, am1); am1 = fmaf(a1.y, wA, am1);
      am1 = fmaf(a1.z, wB, am1); am1 = fmaf(a1.w, wC, am1);
      am2 = fmaf(a2.x, w0, am2); am2 = fmaf(a2.y, wA, am2);
      am2 = fmaf(a2.z, wB, am2); am2 = fmaf(a2.w, wC, am2);
      am3 = fmaf(a3.x, w0, am3); am3 = fmaf(a3.y, wA, am3);
      am3 = fmaf(a3.z, wB, am3); am3 = fmaf(a3.w, wC, am3);
    }
    float z1r[4] = {am0, am1, am2, am3};
    float er[4], x2r[4];
#pragma unroll
    for (int m = 0; m < 4; ++m) {
      er[m] = erff(z1r[m] * ERF_CF);
      x2r[m] = 0.5f * z1r[m] * (1.0f + er[m]);
      X2s[m][t] = x2r[m];
    }
    __syncthreads();  // B2

    // ---- B: Z2 partials over k-slice [kb,kb+64), column j=lane ----
    {
      float pp0 = 0, pp1 = 0, pp2 = 0, pp3 = 0;
#pragma unroll
      for (int k4 = 0; k4 < 64; k4 += 4) {
        int kk = kb + k4;
        float4 y0 = *(const float4*)&X2s[0][kk];
        float4 y1 = *(const float4*)&X2s[1][kk];
        float4 y2 = *(const float4*)&X2s[2][kk];
        float4 y3 = *(const float4*)&X2s[3][kk];
        float wv0 = W2L[kk][(lane + kk) & 63];
        float wv1 = W2L[kk + 1][(lane + kk + 1) & 63];
        float wv2 = W2L[kk + 2][(lane + kk + 2) & 63];
        float wv3 = W2L[kk + 3][(lane + kk + 3) & 63];
        pp0 = fmaf(y0.x, wv0, pp0); pp0 = fmaf(y0.y, wv1, pp0);
        pp0 = fmaf(y0.z, wv2, pp0); pp0 = fmaf(y0.w, wv3, pp0);
        pp1 = fmaf(y1.x, wv0, pp1); pp1 = fmaf(y1.y, wv1, pp1);
        pp1 = fmaf(y1.z, wv2, pp1); pp1 = fmaf(y1.w, wv3, pp1);
        pp2 = fmaf(y2.x, wv0, pp2); pp2 = fmaf(y2.y, wv1, pp2);
        pp2 = fmaf(y2.z, wv2, pp2); pp2 = fmaf(y2.w, wv3, pp2);
        pp3 = fmaf(y3.x, wv0, pp3); pp3 = fmaf(y3.y, wv1, pp3);
        pp3 = fmaf(y3.z, wv2, pp3); pp3 = fmaf(y3.w, wv3, pp3);
      }
      redS[w][0][lane] = pp0;
      redS[w][1][lane] = pp1;
      redS[w][2][lane] = pp2;
      redS[w][3][lane] = pp3;
    }
    __syncthreads();  // B3

    // ---- C: reduce + LN-l2-bwd -> gZ2s (row m = w, col = lane) ----
    {
      float z2 = b2s[lane] + redS[0][w][lane] + redS[1][w][lane] +
                 redS[2][w][lane] + redS[3][w][lane];
      float mu = wsum(z2) * (1.0f / 64.0f);
      float dv = z2 - mu;
      float var = wsum(dv * dv) * (1.0f / 64.0f);
      float stdv = sqrtf(var + 1e-6f);
      float zhat = dv / stdv;
      float lwv = lwS[lane], lbv = lbS[lane];
      float tgt = xvL[kb + lane] - xkL[kb + lane];
      float gg = lwv * (lwv * zhat + lbv - tgt);
      float gs = wsum(gg) * (1.0f / 64.0f);
      float gzs = wsum(gg * zhat) * (1.0f / 64.0f);
      gZ2s[w][lane] = (gg - gs - zhat * gzs) / stdv;
    }
    __syncthreads();  // B4

    // prefetch next step's inputs (hidden under D/E/F compute)
    if (n + 1 < 256) {
      const long nb = chain + (long)(n + 1) * 256;
      rk = XK[nb + t]; rv = XV[nb + t]; rq = XQ[nb + t];
    }

    // ---- D: gZ1[m][c] (old W2 row) fused with w2r update ----
    float gz0, gz1v, gz2v, gz3v;
    {
      float sD0 = 0, sD1 = 0, sD2 = 0, sD3 = 0;
#pragma unroll
      for (int p4 = 0; p4 < 64; p4 += 4) {
        float4 q0 = *(const float4*)&gZ2s[0][p4];
        float4 q1 = *(const float4*)&gZ2s[1][p4];
        float4 q2 = *(const float4*)&gZ2s[2][p4];
        float4 q3 = *(const float4*)&gZ2s[3][p4];
#define DS(J, C)                                              \
  {                                                           \
    float wv = w2r[p4 + J];                                   \
    sD0 = fmaf(q0.C, wv, sD0);                                \
    sD1 = fmaf(q1.C, wv, sD1);                                \
    sD2 = fmaf(q2.C, wv, sD2);                                \
    sD3 = fmaf(q3.C, wv, sD3);                                \
    float u = x2r[0] * q0.C;                                  \
    u = fmaf(x2r[1], q1.C, u);                                \
    u = fmaf(x2r[2], q2.C, u);                                \
    u = fmaf(x2r[3], q3.C, u);                                \
    w2r[p4 + J] = fmaf(-ETA, u, wv);                          \
  }
        DS(0, x) DS(1, y) DS(2, z) DS(3, w)
#undef DS
      }
      float gp0 = 0.5f * (1.0f + er[0]) + z1r[0] * expf(-0.5f * z1r[0] * z1r[0]) * PDF_CF;
      float gp1 = 0.5f * (1.0f + er[1]) + z1r[1] * expf(-0.5f * z1r[1] * z1r[1]) * PDF_CF;
      float gp2 = 0.5f * (1.0f + er[2]) + z1r[2] * expf(-0.5f * z1r[2] * z1r[2]) * PDF_CF;
      float gp3 = 0.5f * (1.0f + er[3]) + z1r[3] * expf(-0.5f * z1r[3] * z1r[3]) * PDF_CF;
      gz0 = sD0 * gp0; gz1v = sD1 * gp1; gz2v = sD2 * gp2; gz3v = sD3 * gp3;
    }
    // commit updated W2 row c to LDS (rotation swizzle, conflict-free)
#pragma unroll
    for (int p = 0; p < 64; ++p) W2L[t][(p + t) & 63] = w2r[p];

    // ---- E: W1[:,c] + b1 update ----
    b1r = fmaf(-ETA, ((gz0 + gz1v) + gz2v) + gz3v, b1r);
#pragma unroll
    for (int k4 = 0; k4 < 64; k4 += 4) {
      float4 a0 = *(const float4*)&xkL[k4];
      float4 a1 = *(const float4*)&xkL[64 + k4];
      float4 a2 = *(const float4*)&xkL[128 + k4];
      float4 a3 = *(const float4*)&xkL[192 + k4];
#define W1S(J, C)                                             \
  {                                                           \
    float u = a0.C * gz0;                                     \
    u = fmaf(a1.C, gz1v, u);                                  \
    u = fmaf(a2.C, gz2v, u);                                  \
    u = fmaf(a3.C, gz3v, u);                                  \
    w1[k4 + J] = fmaf(-ETA, u, w1[k4 + J]);                   \
  }
      W1S(0, x) W1S(1, y) W1S(2, z) W1S(3, w)
#undef W1S
    }
    if (t < 64) {
      float gb2 = ((gZ2s[0][t] + gZ2s[1][t]) + gZ2s[2][t]) + gZ2s[3][t];
      b2s[t] = fmaf(-ETA, gb2, b2s[t]);
    }
    __syncthreads();  // B5: W2L commits visible; X2s/gZ2s reads done

    // ---- F: Z1q with updated W1 ; gelu -> X2s ----
    am0 = b1r; am1 = b1r; am2 = b1r; am3 = b1r;
#pragma unroll
    for (int k4 = 0; k4 < 64; k4 += 4) {
      float4 a0 = *(const float4*)&xqL[k4];
      float4 a1 = *(const float4*)&xqL[64 + k4];
      float4 a2 = *(const float4*)&xqL[128 + k4];
      float4 a3 = *(const float4*)&xqL[192 + k4];
      float w0 = w1[k4], wA = w1[k4 + 1], wB = w1[k4 + 2], wC = w1[k4 + 3];
      am0 = fmaf(a0.x, w0, am0); am0 = fmaf(a0.y, wA, am0);
      am0 = fmaf(a0.z, wB, am0); am0 = fmaf(a0.w, wC, am0);
      am1 = fmaf(a1.x, w0, am1); am1 = fmaf(a1.y, wA, am1);
      am1 = fmaf(a1.z, wB, am1); am1 = fmaf(a1.w, wC, am1);
      am2 = fmaf(a2.x, w0, am2); am2 = fmaf(a2.y, wA, am2);
      am2 = fmaf(a2.z, wB, am2); am2 = fmaf(a2.w, wC, am2);
      am3 = fmaf(a3.x, w0, am3); am3 = fmaf(a3.y, wA, am3);
      am3 = fmaf(a3.z, wB, am3); am3 = fmaf(a3.w, wC, am3);
    }
    X2s[0][t] = 0.5f * am0 * (1.0f + erff(am0 * ERF_CF));
    X2s[1][t] = 0.5f * am1 * (1.0f + erff(am1 * ERF_CF));
    X2s[2][t] = 0.5f * am2 * (1.0f + erff(am2 * ERF_CF));
    X2s[3][t] = 0.5f * am3 * (1.0f + erff(am3 * ERF_CF));
    __syncthreads();  // B6

    // ---- G: Z2q partials with updated W2 ----
    {
      float pp0 = 0, pp1 = 0, pp2 = 0, pp3 = 0;
#pragma unroll
      for (int k4 = 0; k4 < 64; k4 += 4) {
        int kk = kb + k4;
        float4 y0 = *(const float4*)&X2s[0][kk];
        float4 y1 = *(const float4*)&X2s[1][kk];
        float4 y2 = *(const float4*)&X2s[2][kk];
        float4 y3 = *(const float4*)&X2s[3][kk];
        float wv0 = W2L[kk][(lane + kk) & 63];
        float wv1 = W2L[kk + 1][(lane + kk + 1) & 63];
        float wv2 = W2L[kk + 2][(lane + kk + 2) & 63];
        float wv3 = W2L[kk + 3][(lane + kk + 3) & 63];
        pp0 = fmaf(y0.x, wv0, pp0); pp0 = fmaf(y0.y, wv1, pp0);
        pp0 = fmaf(y0.z, wv2, pp0); pp0 = fmaf(y0.w, wv3, pp0);
        pp1 = fmaf(y1.x, wv0, pp1); pp1 = fmaf(y1.y, wv1, pp1);
        pp1 = fmaf(y1.z, wv2, pp1); pp1 = fmaf(y1.w, wv3, pp1);
        pp2 = fmaf(y2.x, wv0, pp2); pp2 = fmaf(y2.y, wv1, pp2);
        pp2 = fmaf(y2.z, wv2, pp2); pp2 = fmaf(y2.w, wv3, pp2);
        pp3 = fmaf(y3.x, wv0, pp3); pp3 = fmaf(y3.y, wv1, pp3);
        pp3 = fmaf(y3.z, wv2, pp3); pp3 = fmaf(y3.w, wv3, pp3);
      }
      redS[w][0][lane] = pp0;
      redS[w][1][lane] = pp1;
      redS[w][2][lane] = pp2;
      redS[w][3][lane] = pp3;
    }
    __syncthreads();  // B7

    // ---- Gr: reduce + LN fwd + residual + output ----
    {
      float z2 = b2s[lane] + redS[0][w][lane] + redS[1][w][lane] +
                 redS[2][w][lane] + redS[3][w][lane];
      float mu = wsum(z2) * (1.0f / 64.0f);
      float dv = z2 - mu;
      float var = wsum(dv * dv) * (1.0f / 64.0f);
      float rstd = rsqrtf(var + 1e-6f);
      float val = lwS[lane] * dv * rstd + lbS[lane] + xqL[kb + lane];
      outp[((long)(b * 1024 + n * 4 + w)) * 256 + h * 64 + lane] = val;
    }
    __syncthreads();  // B8 (protect xk/xv/xq/redS overwrite next iter)
  }
}

// final (4096,64) @ (64,1) + b
__global__ __launch_bounds__(256) void fc3_kernel(const float* __restrict__ f2,
                                                  const float* __restrict__ w,
                                                  const float* __restrict__ bias,
                                                  float* __restrict__ o) {
  int m = blockIdx.x * 4 + (threadIdx.x >> 6);
  int lane = threadIdx.x & 63;
  float v = f2[m * 64 + lane] * w[lane];
  v = wsum(v);
  if (lane == 0) o[m] = v + bias[0];
}

// ---------------------------------------------------------------------------
extern "C" void kernel_launch(void* const* d_in, const int* in_sizes, int n_in,
                              void* d_out, int out_size, void* d_ws, size_t ws_size,
                              hipStream_t stream) {
  const float* x       = (const float*)d_in[0];
  const float* conv1_w = (const float*)d_in[1];
  const float* conv1_b = (const float*)d_in[2];
  const float* convs_w = (const float*)d_in[3];
  const float* convs_b = (const float*)d_in[4];
  const float* ln_w    = (const float*)d_in[5];
  const float* ln_b    = (const float*)d_in[6];
  const float* wq      = (const float*)d_in[7];
  const float* wk      = (const float*)d_in[8];
  const float* wv      = (const float*)d_in[9];
  const float* wo      = (const float*)d_in[10];
  const float* ttt_W1  = (const float*)d_in[11];
  const float* ttt_b1  = (const float*)d_in[12];
  const float* ttt_W2  = (const float*)d_in[13];
  const float* ttt_b2  = (const float*)d_in[14];
  const float* ttt_lnw = (const float*)d_in[15];
  const float* ttt_lnb = (const float*)d_in[16];
  const float* fc_w    = (const float*)d_in[17];
  const float* fc_b    = (const float*)d_in[18];
  const float* fc2_w   = (const float*)d_in[19];
  const float* fc2_b   = (const float*)d_in[20];
  const float* fc3_w   = (const float*)d_in[21];
  const float* fc3_b   = (const float*)d_in[22];

  float* ws = (float*)d_ws;
  float* wt1  = ws + 0;                       // 16384
  float* wt   = ws + 16384;                   // 1572864
  float* bufA = ws + 1589248;                 // 1050624 (B,L+2,256)
  float* bufB = ws + 2639872;                 // 1050624
  float* sum4 = ws + 3690496;                 // 1048576 (B,L,256)
  float* tln  = ws + 4739072;                 // 1048576
  float* XQ   = ws + 5787648;                 // 1048576 (B,H,L,64)
  float* XK   = ws + 6836224;                 // 1048576
  float* XV   = ws + 7884800;                 // 1048576
  float* tout = ws + 8933376;                 // 1048576
  float* tfull = sum4;
  float* h2    = bufA;
  float* f1    = XQ;
  float* f2    = tout;

  const int M = 4096;
  dim3 blk(256);

  zero_halo<<<16, blk, 0, stream>>>(bufA, bufB);
  prep_w<<<6208, blk, 0, stream>>>(conv1_w, convs_w, wt1, wt);

  // conv1 (1x1) + relu -> bufA (halo store)
  gemm_k<1, 1, 0, 1, 0><<<dim3(64, 4), blk, 0, stream>>>(
      x, wt1, conv1_b, nullptr, bufA, nullptr, M, 256, 64, 64, 0);

  // 8 sequential 3-tap convs, accumulate acts 1,3,5,7 into sum4
  for (int i = 0; i < 8; ++i) {
    const float* in = (i % 2 == 0) ? bufA : bufB;
    float* out = (i % 2 == 0) ? bufB : bufA;
    const float* wp = wt + (size_t)i * 196608;
    const float* bp = convs_b + i * 256;
    if (i == 1)
      gemm_k<1, 1, 0, 1, 1><<<dim3(64, 4), blk, 0, stream>>>(
          in, wp, bp, nullptr, out, sum4, M, 256, 768, 256, 1);
    else if (i == 3 || i == 5 || i == 7)
      gemm_k<1, 1, 0, 1, 2><<<dim3(64, 4), blk, 0, stream>>>(
          in, wp, bp, nullptr, out, sum4, M, 256, 768, 256, 1);
    else
      gemm_k<1, 1, 0, 1, 0><<<dim3(64, 4), blk, 0, stream>>>(
          in, wp, bp, nullptr, out, sum4, M, 256, 768, 256, 1);
  }

  // LN #1
  ln_kernel<<<4096, 64, 0, stream>>>(sum4, tln, ln_w, ln_b, 1e-5f);

  // QKV projections with (B,H,L,64) scatter
  gemm_k<0, 0, 0, 2, 0><<<dim3(64, 4), blk, 0, stream>>>(
      tln, wq, nullptr, nullptr, XQ, nullptr, M, 256, 256, 256, 0);
  gemm_k<0, 0, 0, 2, 0><<<dim3(64, 4), blk, 0, stream>>>(
      tln, wk, nullptr, nullptr, XK, nullptr, M, 256, 256, 256, 0);
  gemm_k<0, 0, 0, 2, 0><<<dim3(64, 4), blk, 0, stream>>>(
      tln, wv, nullptr, nullptr, XV, nullptr, M, 256, 256, 256, 0);

  // TTT scan: 16 chains, 256 threads each
  ttt_kernel<<<16, dim3(256), 0, stream>>>(XQ, XK, XV, ttt_W1, ttt_b1, ttt_W2,
                                           ttt_b2, ttt_lnw, ttt_lnb, tout);

  // x + out@wo  (residual = tln)
  gemm_k<0, 0, 1, 0, 0><<<dim3(64, 4), blk, 0, stream>>>(
      tout, wo, nullptr, tln, tfull, nullptr, M, 256, 256, 256, 0);

  // LN #2
  ln_kernel<<<4096, 64, 0, stream>>>(tfull, h2, ln_w, ln_b, 1e-5f);

  // fc (256->512), fc2 (512->64), fc3 (64->1)
  gemm_k<1, 0, 0, 0, 0><<<dim3(64, 8), blk, 0, stream>>>(
      h2, fc_w, fc_b, nullptr, f1, nullptr, M, 512, 256, 256, 0);
  gemm_k<1, 0, 0, 0, 0><<<dim3(64, 1), blk, 0, stream>>>(
      f1, fc2_w, fc2_b, nullptr, f2, nullptr, M, 64, 512, 512, 0);
  fc3_kernel<<<1024, blk, 0, stream>>>(f2, fc3_w, fc3_b, (float*)d_out);
}